// Round 1
// baseline (915.819 us; speedup 1.0000x reference)
//
#include <hip/hip_runtime.h>

// VGRUd: B=32768 rows, 25 GRU steps (h=64), fused logits(78)+softmax, f32.
// Layout: 512 thr/block = 8 waves; lane=(row, q): quad of 4 lanes per row.
//   q0 computes z-pre cols, q1 r-pre, q2 xh, q3 hh (64 cols each).
// Weights in LDS, combined for steps 2..25 (x_in==h): Wc = [Wk64+Uk | Wk64_h | Uk_h],
// bias folded as extra row. Per-64-col groups padded by 4 floats -> the quad's 4
// ds_read_b128 addresses hit disjoint banks. h state in LDS (wave-private rows),
// so the 24-step main loop has NO __syncthreads at all.

#define TPB 512

__device__ __forceinline__ float fsig(float x) {
  return __builtin_amdgcn_rcpf(1.0f + __expf(-x));
}
__device__ __forceinline__ float ftanh2(float x) {
  // tanh(x) = 1 - 2/(exp(2x)+1); saturates correctly at +/-inf
  return 1.0f - 2.0f * __builtin_amdgcn_rcpf(__expf(2.0f * x) + 1.0f);
}
__device__ __forceinline__ float4 ld4s(const float* p) { return *(const float4*)p; }

__global__ __launch_bounds__(TPB, 2) void vgru_kernel(
    const float* __restrict__ x,  const float* __restrict__ Hin,
    const float* __restrict__ Wk, const float* __restrict__ Uk,
    const float* __restrict__ bias, const float* __restrict__ Wd,
    const float* __restrict__ bd, float* __restrict__ out)
{
  // s_buf: phase A = stacked [Wk;Uk] chunk (97 rows x 272); later wc(65x272)+wd(65x80)
  __shared__ __align__(16) float s_buf[26384];
  __shared__ __align__(16) float s_h[128 * 68];

  const int tid = threadIdx.x;
  const int q   = tid & 3;        // gate slice within quad
  const int rl  = tid >> 2;       // local row 0..127 (wave-private range)
  const long row = (long)blockIdx.x * 128 + rl;
  const float* b0 = bias;
  const float* b1 = bias + 192;

  float acc[64];

  // ---------------- phase A: step 1 (h1 = gru(x, H)) ----------------
  // chunk0: stacked rows 0..95 (all Wk rows; cols>=192 (hh) get 0 from x-part)
  for (int idx = tid; idx < 96 * 256; idx += TPB) {
    int kl = idx >> 8, c = idx & 255;
    float v = (c < 192) ? Wk[kl * 192 + c] : 0.0f;
    s_buf[kl * 272 + (c >> 6) * 68 + (c & 63)] = v;
  }
  __syncthreads();

  #pragma unroll
  for (int m = 0; m < 64; m++) acc[m] = 0.0f;

  const float* xrow  = x   + (size_t)row * 128;
  const float* hrowg = Hin + (size_t)row * 64;

  for (int kc = 0; kc < 24; ++kc) {
    float4 xv = ld4s(xrow + 4 * kc);
    #pragma unroll
    for (int jj = 0; jj < 4; jj++) {
      const float* wr = s_buf + (4 * kc + jj) * 272 + q * 68;
      float hk = (jj == 0 ? xv.x : jj == 1 ? xv.y : jj == 2 ? xv.z : xv.w);
      #pragma unroll
      for (int m = 0; m < 16; m++) {
        float4 w4 = ld4s(wr + 4 * m);
        acc[4*m+0] += hk * w4.x; acc[4*m+1] += hk * w4.y;
        acc[4*m+2] += hk * w4.z; acc[4*m+3] += hk * w4.w;
      }
    }
  }
  __syncthreads();

  // chunk1: stacked rows 96..191 (Wk rows 96..127, then Uk rows 0..63) + bias row at local 96
  for (int idx = tid; idx < 96 * 256; idx += TPB) {
    int kl = idx >> 8, c = idx & 255;
    int k = 96 + kl;
    float v;
    if (k < 128) {
      v = (c < 192) ? Wk[k * 192 + c] : 0.0f;
    } else {
      int ku = k - 128;
      if      (c < 128) v = Uk[ku * 192 + c];
      else if (c < 192) v = 0.0f;
      else              v = Uk[ku * 192 + (c - 64)];
    }
    s_buf[kl * 272 + (c >> 6) * 68 + (c & 63)] = v;
  }
  if (tid < 256) {
    int c = tid;
    float v;
    if      (c < 128) v = b0[c] + b1[c];
    else if (c < 192) v = b0[c];
    else              v = b1[c - 64];
    s_buf[96 * 272 + (c >> 6) * 68 + (c & 63)] = v;
  }
  __syncthreads();

  {
    float* hlds = s_h + rl * 68;
    for (int kc = 0; kc < 24; ++kc) {
      float4 xv;
      if (kc < 8) {
        xv = ld4s(xrow + 96 + 4 * kc);
      } else {
        xv = ld4s(hrowg + 4 * kc - 32);
        if (q == 0) *(float4*)(hlds + 4 * kc - 32) = xv;  // stash h_prev = H
      }
      #pragma unroll
      for (int jj = 0; jj < 4; jj++) {
        const float* wr = s_buf + (4 * kc + jj) * 272 + q * 68;
        float hk = (jj == 0 ? xv.x : jj == 1 ? xv.y : jj == 2 ? xv.z : xv.w);
        #pragma unroll
        for (int m = 0; m < 16; m++) {
          float4 w4 = ld4s(wr + 4 * m);
          acc[4*m+0] += hk * w4.x; acc[4*m+1] += hk * w4.y;
          acc[4*m+2] += hk * w4.z; acc[4*m+3] += hk * w4.w;
        }
      }
    }
    #pragma unroll
    for (int m = 0; m < 16; m++) {  // + combined bias
      float4 b4 = ld4s(s_buf + 96 * 272 + q * 68 + 4 * m);
      acc[4*m+0] += b4.x; acc[4*m+1] += b4.y; acc[4*m+2] += b4.z; acc[4*m+3] += b4.w;
    }
  }

  // ---- GRU epilogue: gather 4 gate values per j across the quad, update h in LDS ----
  auto epilogue = [&]() {
    float* hlds = s_h + rl * 68;
    #pragma unroll
    for (int jb = 0; jb < 16; jb++) {
      float4 hp = ld4s(hlds + 4 * jb);
      float hn[4];
      #pragma unroll
      for (int jj = 0; jj < 4; jj++) {
        const int j = 4 * jb + jj;
        float zp = __shfl(acc[j], 0, 4);
        float rp = __shfl(acc[j], 1, 4);
        float xh = __shfl(acc[j], 2, 4);
        float hh = __shfl(acc[j], 3, 4);
        float z  = fsig(zp);
        float rr = fsig(rp);
        float cand = ftanh2(xh + rr * hh);
        float hpj = (jj == 0 ? hp.x : jj == 1 ? hp.y : jj == 2 ? hp.z : hp.w);
        hn[jj] = z * hpj + (1.0f - z) * cand;
      }
      if (q == 0) {
        *(float4*)(hlds + 4 * jb) = make_float4(hn[0], hn[1], hn[2], hn[3]);
      }
    }
  };

  // ---- fused logits (78) + softmax + store for step s ----
  auto logits_store = [&](int s) {
    const float* wd = s_buf + 65 * 272;  // 17680
    float la[20];
    #pragma unroll
    for (int i = 0; i < 5; i++) {
      float4 b4 = ld4s(wd + 64 * 80 + 20 * q + 4 * i);
      la[4*i+0] = b4.x; la[4*i+1] = b4.y; la[4*i+2] = b4.z; la[4*i+3] = b4.w;
    }
    const float* hlds = s_h + rl * 68;
    for (int kc = 0; kc < 16; ++kc) {
      float4 h4 = ld4s(hlds + 4 * kc);
      #pragma unroll
      for (int jj = 0; jj < 4; jj++) {
        const float* wr = wd + (4 * kc + jj) * 80 + 20 * q;
        float hk = (jj == 0 ? h4.x : jj == 1 ? h4.y : jj == 2 ? h4.z : h4.w);
        #pragma unroll
        for (int i = 0; i < 5; i++) {
          float4 w4 = ld4s(wr + 4 * i);
          la[4*i+0] += hk * w4.x; la[4*i+1] += hk * w4.y;
          la[4*i+2] += hk * w4.z; la[4*i+3] += hk * w4.w;
        }
      }
    }
    float mx = -1e30f;
    #pragma unroll
    for (int i = 0; i < 20; i++) { if (20 * q + i < 78) mx = fmaxf(mx, la[i]); }
    mx = fmaxf(mx, __shfl_xor(mx, 1, 4));
    mx = fmaxf(mx, __shfl_xor(mx, 2, 4));
    float sum = 0.0f;
    #pragma unroll
    for (int i = 0; i < 20; i++) {
      float e = (20 * q + i < 78) ? __expf(la[i] - mx) : 0.0f;
      la[i] = e; sum += e;
    }
    sum += __shfl_xor(sum, 1, 4);
    sum += __shfl_xor(sum, 2, 4);
    float inv = __builtin_amdgcn_rcpf(sum);
    float* orow = out + ((long)row * 25 + s) * 78 + 20 * q;
    #pragma unroll
    for (int i = 0; i < 20; i++) {
      if (20 * q + i < 78) orow[i] = la[i] * inv;
    }
  };

  epilogue();          // h1 now in s_h
  __syncthreads();

  // ---- load recurrence weights: wc = [Wk64+Uk | Wk64_h | Uk_h] + bias row; wd = Wd + bd row
  for (int idx = tid; idx < 64 * 256; idx += TPB) {
    int k = idx >> 8, c = idx & 255;
    float v;
    if      (c < 128) v = Wk[k * 192 + c] + Uk[k * 192 + c];
    else if (c < 192) v = Wk[k * 192 + c];
    else              v = Uk[k * 192 + (c - 64)];
    s_buf[k * 272 + (c >> 6) * 68 + (c & 63)] = v;
  }
  if (tid < 256) {
    int c = tid;
    float v;
    if      (c < 128) v = b0[c] + b1[c];
    else if (c < 192) v = b0[c];
    else              v = b1[c - 64];
    s_buf[64 * 272 + (c >> 6) * 68 + (c & 63)] = v;
  }
  for (int idx = tid; idx < 65 * 80; idx += TPB) {
    int k = idx / 80, c = idx % 80;
    float v = 0.0f;
    if (c < 78) v = (k < 64) ? Wd[k * 78 + c] : bd[c];
    s_buf[17680 + k * 80 + c] = v;
  }
  __syncthreads();

  logits_store(0);     // output row for h1

  // ---------------- steps 2..25: barrier-free ----------------
  for (int s = 1; s < 25; ++s) {
    #pragma unroll
    for (int m = 0; m < 16; m++) {   // init from combined-bias row
      float4 b4 = ld4s(s_buf + 64 * 272 + q * 68 + 4 * m);
      acc[4*m+0] = b4.x; acc[4*m+1] = b4.y; acc[4*m+2] = b4.z; acc[4*m+3] = b4.w;
    }
    const float* hlds = s_h + rl * 68;
    for (int kc = 0; kc < 16; ++kc) {
      float4 h4 = ld4s(hlds + 4 * kc);
      #pragma unroll
      for (int jj = 0; jj < 4; jj++) {
        const float* wr = s_buf + (4 * kc + jj) * 272 + q * 68;
        float hk = (jj == 0 ? h4.x : jj == 1 ? h4.y : jj == 2 ? h4.z : h4.w);
        #pragma unroll
        for (int m = 0; m < 16; m++) {
          float4 w4 = ld4s(wr + 4 * m);
          acc[4*m+0] += hk * w4.x; acc[4*m+1] += hk * w4.y;
          acc[4*m+2] += hk * w4.z; acc[4*m+3] += hk * w4.w;
        }
      }
    }
    epilogue();
    logits_store(s);
  }
}

extern "C" void kernel_launch(void* const* d_in, const int* in_sizes, int n_in,
                              void* d_out, int out_size, void* d_ws, size_t ws_size,
                              hipStream_t stream) {
  const float* x   = (const float*)d_in[0];
  const float* H   = (const float*)d_in[1];
  const float* Wk  = (const float*)d_in[2];
  const float* Uk  = (const float*)d_in[3];
  const float* b   = (const float*)d_in[4];
  const float* Wd  = (const float*)d_in[5];
  const float* bd  = (const float*)d_in[6];
  float* out = (float*)d_out;
  // 32768 rows / 128 rows-per-block = 256 blocks (1 per CU)
  vgru_kernel<<<dim3(256), dim3(TPB), 0, stream>>>(x, H, Wk, Uk, b, Wd, bd, out);
}

// Round 2
// 588.252 us; speedup vs baseline: 1.5568x; 1.5568x over previous
//
#include <hip/hip_runtime.h>

// VGRUd v2 — two kernels.
// K1 (recurrence): 256 blocks x 512 thr (8 waves). Lane = (co=lane&31, rs=lane>>5).
//   Lane owns cols {2co,2co+1} of each of the 4 gate blocks, for 8 rows
//   (rowbase = wave*16 + rs*8). acc[4][2][8] = 64 regs; 64 FMA per k vs
//   4 ds_read_b64 (w) + 2 ds_read_b128 (hT). GRU epilogue fully lane-local.
//   h kept transposed in LDS hT[k][row] (wave-private rows -> no barriers in
//   the 24-step main loop). Per-step h also streamed to out[row][step][0:64]
//   (f32 scratch inside the output buffer; kernel2 overwrites with probs).
// K2 (logits+softmax): 6400 blocks x 128 thr. Tile = 128 srows. wdT[80][68] +
//   hT-half[32][132] in LDS (38.6 KB -> 4 blocks/CU). Lane = (co: 5 cols,
//   sg: 16 srows); acc[16][5]; 80 FMA per 9 LDS instr. Softmax via width-16
//   shuffle reduce; stores overwrite the h scratch (own rows only).

#define TPB 512

__device__ __forceinline__ float fsig(float x) {
  return __builtin_amdgcn_rcpf(1.0f + __expf(-x));
}
__device__ __forceinline__ float ftanh2(float x) {
  return 1.0f - 2.0f * __builtin_amdgcn_rcpf(__expf(2.0f * x) + 1.0f);
}

__global__ __launch_bounds__(TPB, 2) void vgru_rec(
    const float* __restrict__ x,  const float* __restrict__ Hin,
    const float* __restrict__ Wk, const float* __restrict__ Uk,
    const float* __restrict__ bias, float* __restrict__ out)
{
  extern __shared__ float smem[];
  float* wc = smem;           // [64][256]  65536 B
  float* hT = smem + 16384;   // [64][132]  33792 B   (k-major, row minor)

  const int tid  = threadIdx.x;
  const int lane = tid & 63, wave = tid >> 6;
  const int co   = lane & 31, rs = lane >> 5;
  const int rowbase = wave * 16 + rs * 8;              // block-local first row
  const int blockbase = blockIdx.x * 128;
  const long grow = (long)blockbase + rowbase;         // global row of r=0
  const int j0 = 2 * co;
  const float* b0 = bias;
  const float* b1 = bias + 192;

  // combined per-gate bias (z: b0+b1, r: b0+b1, xh: b0, hh: b1)
  float bs[4][2];
  #pragma unroll
  for (int d = 0; d < 2; ++d) {
    int j = j0 + d;
    bs[0][d] = b0[j] + b1[j];
    bs[1][d] = b0[64 + j] + b1[64 + j];
    bs[2][d] = b0[128 + j];
    bs[3][d] = b1[128 + j];
  }

  float acc[4][2][8];
  float hprev[2][8];

  auto acc_init = [&]() {
    #pragma unroll
    for (int g = 0; g < 4; ++g)
      #pragma unroll
      for (int d = 0; d < 2; ++d)
        #pragma unroll
        for (int r = 0; r < 8; ++r) acc[g][d][r] = bs[g][d];
  };

  auto accum64 = [&](const float* src) {
    const float* wp = wc + j0;
    const float* hp = src + rowbase;
    #pragma unroll 8
    for (int k = 0; k < 64; ++k) {
      float2 w0 = *(const float2*)(wp + k * 256);
      float2 w1 = *(const float2*)(wp + k * 256 + 64);
      float2 w2 = *(const float2*)(wp + k * 256 + 128);
      float2 w3 = *(const float2*)(wp + k * 256 + 192);
      float4 ha = *(const float4*)(hp + k * 132);
      float4 hb = *(const float4*)(hp + k * 132 + 4);
      float hr[8] = {ha.x, ha.y, ha.z, ha.w, hb.x, hb.y, hb.z, hb.w};
      #pragma unroll
      for (int r = 0; r < 8; ++r) {
        acc[0][0][r] += w0.x * hr[r]; acc[0][1][r] += w0.y * hr[r];
        acc[1][0][r] += w1.x * hr[r]; acc[1][1][r] += w1.y * hr[r];
        acc[2][0][r] += w2.x * hr[r]; acc[2][1][r] += w2.y * hr[r];
        acc[3][0][r] += w3.x * hr[r]; acc[3][1][r] += w3.y * hr[r];
      }
    }
  };

  auto epilogue_and_store = [&](int s) {
    #pragma unroll
    for (int d = 0; d < 2; ++d)
      #pragma unroll
      for (int r = 0; r < 8; ++r) {
        float z  = fsig(acc[0][d][r]);
        float rg = fsig(acc[1][d][r]);
        float cand = ftanh2(acc[2][d][r] + rg * acc[3][d][r]);
        hprev[d][r] = cand + z * (hprev[d][r] - cand);
      }
    #pragma unroll
    for (int d = 0; d < 2; ++d) {
      float* hw = hT + (j0 + d) * 132 + rowbase;
      *(float4*)(hw)     = make_float4(hprev[d][0], hprev[d][1], hprev[d][2], hprev[d][3]);
      *(float4*)(hw + 4) = make_float4(hprev[d][4], hprev[d][5], hprev[d][6], hprev[d][7]);
    }
    #pragma unroll
    for (int r = 0; r < 8; ++r) {
      *(float2*)&out[((size_t)(grow + r) * 25 + s) * 78 + j0] =
          make_float2(hprev[0][r], hprev[1][r]);
    }
  };

  // ---------------- phase A: step 0, K=192 in 3 chunks of 64 ----------------
  // chunk 0: Wk rows 0..63, input x cols 0..63
  for (int idx = tid; idx < 16384; idx += TPB) {
    int k = idx >> 8, c = idx & 255;
    wc[idx] = (c < 192) ? Wk[k * 192 + c] : 0.0f;
  }
  for (int p = 0; p < 16; ++p) {           // wave-private transpose stage
    int row = wave * 16 + p;
    hT[lane * 132 + row] = x[(size_t)(blockbase + row) * 128 + lane];
  }
  __syncthreads();
  acc_init();
  accum64(hT);
  __syncthreads();

  // chunk 1: Wk rows 64..127, x cols 64..127
  for (int idx = tid; idx < 16384; idx += TPB) {
    int k = idx >> 8, c = idx & 255;
    wc[idx] = (c < 192) ? Wk[(64 + k) * 192 + c] : 0.0f;
  }
  for (int p = 0; p < 16; ++p) {
    int row = wave * 16 + p;
    hT[lane * 132 + row] = x[(size_t)(blockbase + row) * 128 + 64 + lane];
  }
  __syncthreads();
  accum64(hT);
  __syncthreads();

  // chunk 2: Uk rows (gate remap), input H
  for (int idx = tid; idx < 16384; idx += TPB) {
    int k = idx >> 8, c = idx & 255;
    float v;
    if      (c < 128) v = Uk[k * 192 + c];
    else if (c < 192) v = 0.0f;
    else              v = Uk[k * 192 + 128 + (c - 192)];
    wc[idx] = v;
  }
  for (int p = 0; p < 16; ++p) {
    int row = wave * 16 + p;
    hT[lane * 132 + row] = Hin[(size_t)(blockbase + row) * 64 + lane];
  }
  __syncthreads();
  accum64(hT);
  #pragma unroll
  for (int r = 0; r < 8; ++r) {
    float2 hv = *(const float2*)&Hin[(size_t)(grow + r) * 64 + j0];
    hprev[0][r] = hv.x; hprev[1][r] = hv.y;
  }
  epilogue_and_store(0);
  __syncthreads();

  // main-loop combined weights: [Wk64+Uk | Wk64+Uk | Wk64_xh | Uk_hh]
  for (int idx = tid; idx < 16384; idx += TPB) {
    int k = idx >> 8, c = idx & 255;
    float v;
    if      (c < 128) v = Wk[k * 192 + c] + Uk[k * 192 + c];
    else if (c < 192) v = Wk[k * 192 + c];
    else              v = Uk[k * 192 + 128 + (c - 192)];
    wc[idx] = v;
  }
  __syncthreads();

  // ---------------- steps 1..24: barrier-free ----------------
  for (int s = 1; s < 25; ++s) {
    acc_init();
    accum64(hT);
    epilogue_and_store(s);
  }
}

// ---------------- kernel 2: logits + softmax ----------------
__global__ __launch_bounds__(128, 2) void vgru_logits(
    const float* __restrict__ Wd, const float* __restrict__ bd,
    float* __restrict__ out)
{
  __shared__ float wdT[80 * 68];   // [c][k], stride 68
  __shared__ float hTt[32 * 132];  // [k][srow], half-K tile

  const int tid  = threadIdx.x;
  const int lane = tid & 63, wave = tid >> 6;
  const int co   = lane & 15, sg = lane >> 4;
  const long srowbase = (long)blockIdx.x * 128;
  const int sloc = wave * 64 + sg * 16;    // lane's first local srow

  // stage WdT (transposed), zero pad rows 78,79
  for (int idx = tid; idx < 78 * 64; idx += 128) {
    int k = idx / 78, c = idx - 78 * k;
    wdT[c * 68 + k] = Wd[idx];
  }
  {
    int k2 = tid & 63, c2 = 78 + (tid >> 6);
    wdT[c2 * 68 + k2] = 0.0f;   // 128 threads cover rows 78,79
  }

  float bdv[5];
  #pragma unroll
  for (int ci = 0; ci < 5; ++ci) {
    int c = 5 * co + ci;
    bdv[ci] = (c < 78) ? bd[c] : 0.0f;
  }

  float acc[16][5];
  #pragma unroll
  for (int s = 0; s < 16; ++s)
    #pragma unroll
    for (int ci = 0; ci < 5; ++ci) acc[s][ci] = bdv[ci];

  const float* wp0 = wdT + (5 * co + 0) * 68;
  const float* wp1 = wdT + (5 * co + 1) * 68;
  const float* wp2 = wdT + (5 * co + 2) * 68;
  const float* wp3 = wdT + (5 * co + 3) * 68;
  const float* wp4 = wdT + (5 * co + 4) * 68;

  for (int kh = 0; kh < 2; ++kh) {
    // stage h half-tile: hTt[k][sr] = out[srow][kh*32+k]  (h scratch cols 0..63)
    for (int idx = tid; idx < 128 * 32; idx += 128) {
      int kk = idx & 31, sr = idx >> 5;
      hTt[kk * 132 + sr] = out[(srowbase + sr) * 78 + kh * 32 + kk];
    }
    __syncthreads();
    const int kb = kh * 32;
    const float* hp = hTt + sloc;
    #pragma unroll 4
    for (int k = 0; k < 32; ++k) {
      float wv0 = wp0[kb + k], wv1 = wp1[kb + k], wv2 = wp2[kb + k],
            wv3 = wp3[kb + k], wv4 = wp4[kb + k];
      #pragma unroll
      for (int m = 0; m < 4; ++m) {
        float4 h4 = *(const float4*)(hp + k * 132 + 4 * m);
        float hv[4] = {h4.x, h4.y, h4.z, h4.w};
        #pragma unroll
        for (int i = 0; i < 4; ++i) {
          const int s = 4 * m + i;
          acc[s][0] += hv[i] * wv0; acc[s][1] += hv[i] * wv1;
          acc[s][2] += hv[i] * wv2; acc[s][3] += hv[i] * wv3;
          acc[s][4] += hv[i] * wv4;
        }
      }
    }
    __syncthreads();
  }

  // softmax per srow across the 16-lane co-group
  #pragma unroll
  for (int s = 0; s < 16; ++s) {
    float mx = -1e30f;
    #pragma unroll
    for (int ci = 0; ci < 5; ++ci)
      if (5 * co + ci < 78) mx = fmaxf(mx, acc[s][ci]);
    mx = fmaxf(mx, __shfl_xor(mx, 1, 16));
    mx = fmaxf(mx, __shfl_xor(mx, 2, 16));
    mx = fmaxf(mx, __shfl_xor(mx, 4, 16));
    mx = fmaxf(mx, __shfl_xor(mx, 8, 16));
    float sum = 0.0f;
    #pragma unroll
    for (int ci = 0; ci < 5; ++ci) {
      float e = (5 * co + ci < 78) ? __expf(acc[s][ci] - mx) : 0.0f;
      acc[s][ci] = e; sum += e;
    }
    sum += __shfl_xor(sum, 1, 16);
    sum += __shfl_xor(sum, 2, 16);
    sum += __shfl_xor(sum, 4, 16);
    sum += __shfl_xor(sum, 8, 16);
    float inv = __builtin_amdgcn_rcpf(sum);
    long srow = srowbase + sloc + s;
    #pragma unroll
    for (int ci = 0; ci < 5; ++ci)
      if (5 * co + ci < 78) out[srow * 78 + 5 * co + ci] = acc[s][ci] * inv;
  }
}

extern "C" void kernel_launch(void* const* d_in, const int* in_sizes, int n_in,
                              void* d_out, int out_size, void* d_ws, size_t ws_size,
                              hipStream_t stream) {
  const float* x   = (const float*)d_in[0];
  const float* H   = (const float*)d_in[1];
  const float* Wk  = (const float*)d_in[2];
  const float* Uk  = (const float*)d_in[3];
  const float* b   = (const float*)d_in[4];
  const float* Wd  = (const float*)d_in[5];
  const float* bd  = (const float*)d_in[6];
  float* out = (float*)d_out;

  const int dynLds = (16384 + 64 * 132) * 4;   // 99328 B
  hipFuncSetAttribute((const void*)vgru_rec,
                      hipFuncAttributeMaxDynamicSharedMemorySize, dynLds);
  vgru_rec<<<dim3(256), dim3(TPB), dynLds, stream>>>(x, H, Wk, Uk, b, out);
  vgru_logits<<<dim3(6400), dim3(128), 0, stream>>>(Wd, bd, out);
}

// Round 3
// 239.424 us; speedup vs baseline: 3.8251x; 2.4569x over previous
//
#include <hip/hip_runtime.h>
#include <hip/hip_bf16.h>

// VGRUd v3 — MFMA (3xbf16 = f32-grade) recurrence.
// K_A: step 1 (K=192) in f32 VALU (proven v2 phase-A); h1 -> out scratch.
// K_B: 25x { logits(78)+softmax+store; GRU step } entirely per-wave:
//   256 thr = 4 waves x 32 rows; weights as pre-split hi/lo bf16 LDS
//   fragments (lane-major 16B -> conflict-free); mfma_f32_16x16x32_bf16;
//   DPP row_ror softmax reduce; barrier-free main loop.

typedef short bf16x8 __attribute__((ext_vector_type(8)));
typedef float f32x4 __attribute__((ext_vector_type(4)));

#define TPB_A 512
#define TPB_B 256

__device__ __forceinline__ float fsig(float x) {
  return __builtin_amdgcn_rcpf(1.0f + __expf(-x));
}
__device__ __forceinline__ float ftanh2(float x) {
  return 1.0f - 2.0f * __builtin_amdgcn_rcpf(__expf(2.0f * x) + 1.0f);
}
template <int CTRL>
__device__ __forceinline__ float dppror(float x) {
  return __int_as_float(
      __builtin_amdgcn_update_dpp(0, __float_as_int(x), CTRL, 0xf, 0xf, true));
}
__device__ __forceinline__ unsigned short bf16hi(unsigned int u) {
  return (unsigned short)(u >> 16);
}
__device__ __forceinline__ unsigned short bf16rne(float f) {
  unsigned int u = __float_as_uint(f);
  return (unsigned short)((u + 0x7fffu + ((u >> 16) & 1u)) >> 16);
}

// ---------------- Kernel A: step 1 (f32, v2-proven structure) ----------------
__global__ __launch_bounds__(TPB_A, 2) void vgru_step0(
    const float* __restrict__ x,  const float* __restrict__ Hin,
    const float* __restrict__ Wk, const float* __restrict__ Uk,
    const float* __restrict__ bias, float* __restrict__ out)
{
  extern __shared__ float smem[];
  float* wc = smem;           // [64][256]
  float* hT = smem + 16384;   // [64][132]

  const int tid  = threadIdx.x;
  const int lane = tid & 63, wave = tid >> 6;
  const int co   = lane & 31, rs = lane >> 5;
  const int rowbase = wave * 16 + rs * 8;
  const int blockbase = blockIdx.x * 128;
  const long grow = (long)blockbase + rowbase;
  const int j0 = 2 * co;
  const float* b0 = bias;
  const float* b1 = bias + 192;

  float bs[4][2];
  #pragma unroll
  for (int d = 0; d < 2; ++d) {
    int j = j0 + d;
    bs[0][d] = b0[j] + b1[j];
    bs[1][d] = b0[64 + j] + b1[64 + j];
    bs[2][d] = b0[128 + j];
    bs[3][d] = b1[128 + j];
  }

  float acc[4][2][8];
  #pragma unroll
  for (int g = 0; g < 4; ++g)
    #pragma unroll
    for (int d = 0; d < 2; ++d)
      #pragma unroll
      for (int r = 0; r < 8; ++r) acc[g][d][r] = bs[g][d];

  auto accum64 = [&]() {
    const float* wp = wc + j0;
    const float* hp = hT + rowbase;
    #pragma unroll 8
    for (int k = 0; k < 64; ++k) {
      float2 w0 = *(const float2*)(wp + k * 256);
      float2 w1 = *(const float2*)(wp + k * 256 + 64);
      float2 w2 = *(const float2*)(wp + k * 256 + 128);
      float2 w3 = *(const float2*)(wp + k * 256 + 192);
      float4 ha = *(const float4*)(hp + k * 132);
      float4 hb = *(const float4*)(hp + k * 132 + 4);
      float hr[8] = {ha.x, ha.y, ha.z, ha.w, hb.x, hb.y, hb.z, hb.w};
      #pragma unroll
      for (int r = 0; r < 8; ++r) {
        acc[0][0][r] += w0.x * hr[r]; acc[0][1][r] += w0.y * hr[r];
        acc[1][0][r] += w1.x * hr[r]; acc[1][1][r] += w1.y * hr[r];
        acc[2][0][r] += w2.x * hr[r]; acc[2][1][r] += w2.y * hr[r];
        acc[3][0][r] += w3.x * hr[r]; acc[3][1][r] += w3.y * hr[r];
      }
    }
  };

  // chunk 0: Wk rows 0..63, x cols 0..63
  for (int idx = tid; idx < 16384; idx += TPB_A) {
    int k = idx >> 8, c = idx & 255;
    wc[idx] = (c < 192) ? Wk[k * 192 + c] : 0.0f;
  }
  for (int p = 0; p < 16; ++p) {
    int row = wave * 16 + p;
    hT[lane * 132 + row] = x[(size_t)(blockbase + row) * 128 + lane];
  }
  __syncthreads();
  accum64();
  __syncthreads();

  // chunk 1: Wk rows 64..127, x cols 64..127
  for (int idx = tid; idx < 16384; idx += TPB_A) {
    int k = idx >> 8, c = idx & 255;
    wc[idx] = (c < 192) ? Wk[(64 + k) * 192 + c] : 0.0f;
  }
  for (int p = 0; p < 16; ++p) {
    int row = wave * 16 + p;
    hT[lane * 132 + row] = x[(size_t)(blockbase + row) * 128 + 64 + lane];
  }
  __syncthreads();
  accum64();
  __syncthreads();

  // chunk 2: Uk (gate remap), input H
  for (int idx = tid; idx < 16384; idx += TPB_A) {
    int k = idx >> 8, c = idx & 255;
    float v;
    if      (c < 128) v = Uk[k * 192 + c];
    else if (c < 192) v = 0.0f;
    else              v = Uk[k * 192 + 128 + (c - 192)];
    wc[idx] = v;
  }
  for (int p = 0; p < 16; ++p) {
    int row = wave * 16 + p;
    hT[lane * 132 + row] = Hin[(size_t)(blockbase + row) * 64 + lane];
  }
  __syncthreads();
  accum64();

  #pragma unroll
  for (int r = 0; r < 8; ++r) {
    float2 hv = *(const float2*)&Hin[(size_t)(grow + r) * 64 + j0];
    float hp[2] = {hv.x, hv.y};
    float hn[2];
    #pragma unroll
    for (int d = 0; d < 2; ++d) {
      float z  = fsig(acc[0][d][r]);
      float rg = fsig(acc[1][d][r]);
      float cand = ftanh2(acc[2][d][r] + rg * acc[3][d][r]);
      hn[d] = cand + z * (hp[d] - cand);
    }
    // h1 scratch lives at out[row][step 0][0:64] (f32); overwritten by probs later
    *(float2*)&out[(size_t)(grow + r) * 1950 + j0] = make_float2(hn[0], hn[1]);
  }
}

// ---------------- Kernel B: 25 steps, MFMA 3xbf16 ----------------
__global__ __launch_bounds__(TPB_B, 1) void vgru_main(
    const float* __restrict__ Wk, const float* __restrict__ Uk,
    const float* __restrict__ bias, const float* __restrict__ Wd,
    const float* __restrict__ bd, float* __restrict__ out)
{
  extern __shared__ float smem[];
  // floats: [0,8192) gateHi | [8192,16384) gateLo | [16384,18944) wdHi
  //         [18944,21504) wdLo | [21504,30208) hT[128][68]
  float* hT = smem + 21504;

  const int tid  = threadIdx.x;
  const int lane = tid & 63, wave = tid >> 6;
  const int g = lane >> 4, n = lane & 15;
  const int lrow0 = wave * 32;
  const int blockbase = blockIdx.x * 128;
  const float* b0 = bias;
  const float* b1 = bias + 192;

  // ---- stage weight fragments (hi/lo split, frag-major: [fr][lane] 16B) ----
  for (int idx = tid; idx < 42 * 64; idx += TPB_B) {
    int fr = idx >> 6, ln = idx & 63;
    int lg = ln >> 4, lnn = ln & 15;
    bool iswd = (fr >= 32);
    int fr2 = iswd ? fr - 32 : fr;
    int nt = fr2 >> 1, ks = fr2 & 1;
    int k0 = ks * 32 + lg * 8;
    int c  = nt * 16 + lnn;
    float f[8];
    #pragma unroll
    for (int j = 0; j < 8; ++j) {
      int k = k0 + j;
      float v;
      if (!iswd) {
        if      (c < 128) v = Wk[k * 192 + c] + Uk[k * 192 + c];
        else if (c < 192) v = Wk[k * 192 + c];
        else              v = Uk[k * 192 + 128 + (c - 192)];
      } else {
        v = (c < 78) ? Wd[k * 78 + c] : 0.0f;
      }
      f[j] = v;
    }
    unsigned int hi[8], lo[8];
    #pragma unroll
    for (int j = 0; j < 8; ++j) {
      unsigned int u = __float_as_uint(f[j]);
      hi[j] = u >> 16;
      float fh = __uint_as_float(u & 0xffff0000u);
      lo[j] = bf16rne(f[j] - fh);
    }
    uint4 ph = make_uint4(hi[0] | (hi[1] << 16), hi[2] | (hi[3] << 16),
                          hi[4] | (hi[5] << 16), hi[6] | (hi[7] << 16));
    uint4 pl = make_uint4(lo[0] | (lo[1] << 16), lo[2] | (lo[3] << 16),
                          lo[4] | (lo[5] << 16), lo[6] | (lo[7] << 16));
    int fi = fr2 * 64 + ln;
    if (!iswd) {
      ((uint4*)(smem))[fi]         = ph;
      ((uint4*)(smem + 8192))[fi]  = pl;
    } else {
      ((uint4*)(smem + 16384))[fi] = ph;
      ((uint4*)(smem + 18944))[fi] = pl;
    }
  }

  // ---- load h1 (from out scratch) into hT[128][68] ----
  for (int i = tid; i < 4096; i += TPB_B) {
    int r = i >> 5, c2 = (i & 31) * 2;
    float2 v = *(const float2*)(out + (size_t)(blockbase + r) * 1950 + c2);
    *(float2*)(hT + r * 68 + c2) = v;
  }
  __syncthreads();

  const bf16x8* GH = (const bf16x8*)(smem);
  const bf16x8* GL = (const bf16x8*)(smem + 8192);
  const bf16x8* WH = (const bf16x8*)(smem + 16384);
  const bf16x8* WL = (const bf16x8*)(smem + 18944);

  // per-lane bias values: gate biases at col jt*16+n; bd at col nt*16+n
  float bz[4], br[4], bxh[4], bhh[4], bdv[5];
  #pragma unroll
  for (int jt = 0; jt < 4; ++jt) {
    int c = jt * 16 + n;
    bz[jt]  = b0[c] + b1[c];
    br[jt]  = b0[64 + c] + b1[64 + c];
    bxh[jt] = b0[128 + c];
    bhh[jt] = b1[128 + c];
  }
  #pragma unroll
  for (int nt = 0; nt < 5; ++nt) {
    int c = nt * 16 + n;
    bdv[nt] = (c < 78) ? bd[c] : 0.0f;
  }

  #pragma unroll 1
  for (int s = 0; s < 25; ++s) {
    // ---- A fragments (h, split hi/lo) ----
    bf16x8 Ah[2][2], Al[2][2];
    #pragma unroll
    for (int mt = 0; mt < 2; ++mt)
      #pragma unroll
      for (int ks = 0; ks < 2; ++ks) {
        const float* hp = hT + (lrow0 + mt * 16 + n) * 68 + ks * 32 + g * 8;
        float4 v0 = *(const float4*)hp;
        float4 v1 = *(const float4*)(hp + 4);
        float f[8] = {v0.x, v0.y, v0.z, v0.w, v1.x, v1.y, v1.z, v1.w};
        bf16x8 ah, al;
        #pragma unroll
        for (int j = 0; j < 8; ++j) {
          unsigned int u = __float_as_uint(f[j]);
          ah[j] = (short)(u >> 16);
          float fh = __uint_as_float(u & 0xffff0000u);
          al[j] = (short)bf16rne(f[j] - fh);
        }
        Ah[mt][ks] = ah; Al[mt][ks] = al;
      }

    // ---- logits ----
    f32x4 L[2][5];
    #pragma unroll
    for (int mt = 0; mt < 2; ++mt)
      #pragma unroll
      for (int nt = 0; nt < 5; ++nt)
        L[mt][nt] = (f32x4){bdv[nt], bdv[nt], bdv[nt], bdv[nt]};
    #pragma unroll
    for (int nt = 0; nt < 5; ++nt)
      #pragma unroll
      for (int ks = 0; ks < 2; ++ks) {
        bf16x8 wh = WH[(nt * 2 + ks) * 64 + lane];
        bf16x8 wl = WL[(nt * 2 + ks) * 64 + lane];
        #pragma unroll
        for (int mt = 0; mt < 2; ++mt) {
          L[mt][nt] = __builtin_amdgcn_mfma_f32_16x16x32_bf16(Ah[mt][ks], wh, L[mt][nt], 0, 0, 0);
          L[mt][nt] = __builtin_amdgcn_mfma_f32_16x16x32_bf16(Al[mt][ks], wh, L[mt][nt], 0, 0, 0);
          L[mt][nt] = __builtin_amdgcn_mfma_f32_16x16x32_bf16(Ah[mt][ks], wl, L[mt][nt], 0, 0, 0);
        }
      }

    // ---- softmax + store (DPP row reduce over the 16 col-lanes) ----
    #pragma unroll
    for (int mt = 0; mt < 2; ++mt)
      #pragma unroll
      for (int rr = 0; rr < 4; ++rr) {
        float v0 = L[mt][0][rr], v1 = L[mt][1][rr], v2 = L[mt][2][rr],
              v3 = L[mt][3][rr];
        float v4 = (n < 14) ? L[mt][4][rr] : -1e30f;
        float mx = fmaxf(fmaxf(fmaxf(v0, v1), fmaxf(v2, v3)), v4);
        mx = fmaxf(mx, dppror<0x128>(mx));
        mx = fmaxf(mx, dppror<0x124>(mx));
        mx = fmaxf(mx, dppror<0x122>(mx));
        mx = fmaxf(mx, dppror<0x121>(mx));
        float e0 = __expf(v0 - mx), e1 = __expf(v1 - mx), e2 = __expf(v2 - mx),
              e3 = __expf(v3 - mx);
        float e4 = (n < 14) ? __expf(v4 - mx) : 0.0f;
        float sm = e0 + e1 + e2 + e3 + e4;
        sm += dppror<0x128>(sm);
        sm += dppror<0x124>(sm);
        sm += dppror<0x122>(sm);
        sm += dppror<0x121>(sm);
        float inv = __builtin_amdgcn_rcpf(sm);
        size_t grow = (size_t)blockbase + lrow0 + mt * 16 + g * 4 + rr;
        float* orow = out + (grow * 25 + s) * 78;
        orow[n]      = e0 * inv;
        orow[16 + n] = e1 * inv;
        orow[32 + n] = e2 * inv;
        orow[48 + n] = e3 * inv;
        if (n < 14) orow[64 + n] = e4 * inv;
      }

    // ---- GRU gates -> h_{s+1} ----
    if (s < 24) {
      #pragma unroll
      for (int jt = 0; jt < 4; ++jt) {
        f32x4 G[2][4];
        #pragma unroll
        for (int mt = 0; mt < 2; ++mt) {
          G[mt][0] = (f32x4){bz[jt], bz[jt], bz[jt], bz[jt]};
          G[mt][1] = (f32x4){br[jt], br[jt], br[jt], br[jt]};
          G[mt][2] = (f32x4){bxh[jt], bxh[jt], bxh[jt], bxh[jt]};
          G[mt][3] = (f32x4){bhh[jt], bhh[jt], bhh[jt], bhh[jt]};
        }
        #pragma unroll
        for (int gg = 0; gg < 4; ++gg) {
          int ntb = gg * 4 + jt;
          #pragma unroll
          for (int ks = 0; ks < 2; ++ks) {
            bf16x8 wh = GH[(ntb * 2 + ks) * 64 + lane];
            bf16x8 wl = GL[(ntb * 2 + ks) * 64 + lane];
            #pragma unroll
            for (int mt = 0; mt < 2; ++mt) {
              G[mt][gg] = __builtin_amdgcn_mfma_f32_16x16x32_bf16(Ah[mt][ks], wh, G[mt][gg], 0, 0, 0);
              G[mt][gg] = __builtin_amdgcn_mfma_f32_16x16x32_bf16(Al[mt][ks], wh, G[mt][gg], 0, 0, 0);
              G[mt][gg] = __builtin_amdgcn_mfma_f32_16x16x32_bf16(Ah[mt][ks], wl, G[mt][gg], 0, 0, 0);
            }
          }
        }
        #pragma unroll
        for (int mt = 0; mt < 2; ++mt)
          #pragma unroll
          for (int rr = 0; rr < 4; ++rr) {
            int m = lrow0 + mt * 16 + g * 4 + rr;
            float* hp = hT + m * 68 + jt * 16 + n;
            float hpv = *hp;
            float z  = fsig(G[mt][0][rr]);
            float rg = fsig(G[mt][1][rr]);
            float cand = ftanh2(G[mt][2][rr] + rg * G[mt][3][rr]);
            *hp = cand + z * (hpv - cand);
          }
      }
    }
  }
}

extern "C" void kernel_launch(void* const* d_in, const int* in_sizes, int n_in,
                              void* d_out, int out_size, void* d_ws, size_t ws_size,
                              hipStream_t stream) {
  const float* x   = (const float*)d_in[0];
  const float* H   = (const float*)d_in[1];
  const float* Wk  = (const float*)d_in[2];
  const float* Uk  = (const float*)d_in[3];
  const float* b   = (const float*)d_in[4];
  const float* Wd  = (const float*)d_in[5];
  const float* bd  = (const float*)d_in[6];
  float* out = (float*)d_out;
  (void)d_ws; (void)ws_size; (void)in_sizes; (void)n_in; (void)out_size;

  const int ldsA = (16384 + 64 * 132) * 4;   // 99328 B
  const int ldsB = 30208 * 4;                // 120832 B
  hipFuncSetAttribute((const void*)vgru_step0,
                      hipFuncAttributeMaxDynamicSharedMemorySize, ldsA);
  hipFuncSetAttribute((const void*)vgru_main,
                      hipFuncAttributeMaxDynamicSharedMemorySize, ldsB);
  vgru_step0<<<dim3(256), dim3(TPB_A), ldsA, stream>>>(x, H, Wk, Uk, b, out);
  vgru_main<<<dim3(256), dim3(TPB_B), ldsB, stream>>>(Wk, Uk, b, Wd, bd, out);
}

// Round 4
// 166.921 us; speedup vs baseline: 5.4865x; 1.4344x over previous
//
#include <hip/hip_runtime.h>

// VGRUd v4 — single kernel, persistent-register gate weights.
// 256 blocks x 512 thr (8 waves), 128 rows/block.
// Wave w: gate col-slice jt=w&3 (cols jt*16.. across all 4 gates), rows (w>>2)*64..+64.
//   Gate weights for that slice: 16 bf16x8 frags = 64 VGPR, loaded ONCE (no LDS re-read).
// Logits: wave w handles rows w*16..+16, Wd streamed from LDS (20 KB/step/wave).
// h double-buffered in LDS -> exactly 1 __syncthreads per step.
// Step 1 (K=192) fused: 3 staged LDS weight chunks + MFMA, A-frags direct from global.
// 3xbf16 MFMA emulation (hi*hi + lo*hi + hi*lo) for f32-grade accuracy.

typedef short bf16x8 __attribute__((ext_vector_type(8)));
typedef float f32x4 __attribute__((ext_vector_type(4)));

#define TPB 512

__device__ __forceinline__ float fsig(float x) {
  return __builtin_amdgcn_rcpf(1.0f + __expf(-x));
}
__device__ __forceinline__ float ftanh2(float x) {
  return 1.0f - 2.0f * __builtin_amdgcn_rcpf(__expf(2.0f * x) + 1.0f);
}
template <int CTRL>
__device__ __forceinline__ float dppror(float x) {
  return __int_as_float(
      __builtin_amdgcn_update_dpp(0, __float_as_int(x), CTRL, 0xf, 0xf, true));
}
__device__ __forceinline__ unsigned pack_hi16(float a, float b) {
  // dst = [hi16(a) | hi16(b)<<16]  (truncation)
  return __builtin_amdgcn_perm(__float_as_uint(b), __float_as_uint(a), 0x07060302u);
}
__device__ __forceinline__ float truncbf(float a) {
  return __uint_as_float(__float_as_uint(a) & 0xffff0000u);
}
__device__ __forceinline__ void split8(const float f[8], bf16x8& ah, bf16x8& al) {
  uint4 ph, pl;
  ph.x = pack_hi16(f[0], f[1]); ph.y = pack_hi16(f[2], f[3]);
  ph.z = pack_hi16(f[4], f[5]); ph.w = pack_hi16(f[6], f[7]);
  pl.x = pack_hi16(f[0] - truncbf(f[0]), f[1] - truncbf(f[1]));
  pl.y = pack_hi16(f[2] - truncbf(f[2]), f[3] - truncbf(f[3]));
  pl.z = pack_hi16(f[4] - truncbf(f[4]), f[5] - truncbf(f[5]));
  pl.w = pack_hi16(f[6] - truncbf(f[6]), f[7] - truncbf(f[7]));
  ah = __builtin_bit_cast(bf16x8, ph);
  al = __builtin_bit_cast(bf16x8, pl);
}
__device__ __forceinline__ void splitA_lds(const float* p, bf16x8& ah, bf16x8& al) {
  float4 v0 = *(const float4*)p;
  float4 v1 = *(const float4*)(p + 4);
  float f[8] = {v0.x, v0.y, v0.z, v0.w, v1.x, v1.y, v1.z, v1.w};
  split8(f, ah, al);
}

__global__ __launch_bounds__(TPB, 2) void vgru_all(
    const float* __restrict__ x, const float* __restrict__ Hin,
    const float* __restrict__ Wk, const float* __restrict__ Uk,
    const float* __restrict__ bias, const float* __restrict__ Wd,
    const float* __restrict__ bd, float* __restrict__ out)
{
  extern __shared__ float smem[];
  float* wdHi  = smem;            // [10 frags][64 lanes][4]   10240 B
  float* wdLo  = smem + 2560;
  float* bufA  = smem + 5120;     // h [128][68] f32           34816 B
  float* bufB  = smem + 13824;
  float* chkHi = smem + 22528;    // step-1 chunk [32 frags]   32768 B
  float* chkLo = smem + 30720;    // total 155648 B

  const int tid  = threadIdx.x;
  const int lane = tid & 63, w = tid >> 6;
  const int g = lane >> 4, n = lane & 15;
  const int jt = w & 3;                 // gate col-slice
  const int row0g = (w >> 2) * 64;      // gate rows base (local)
  const int row0l = w * 16;             // logits rows base (local)
  const int blockbase = blockIdx.x * 128;
  const float* b0 = bias;
  const float* b1 = bias + 192;

  // ---- stage Wd frags (hi/lo) ----
  for (int idx = tid; idx < 640; idx += TPB) {
    int fr = idx >> 6, ln = idx & 63;
    int nt = fr >> 1, ks = fr & 1;
    int lg = ln >> 4, lnn = ln & 15;
    int c = nt * 16 + lnn;
    float f[8];
    #pragma unroll
    for (int j = 0; j < 8; ++j) {
      int k = ks * 32 + lg * 8 + j;
      f[j] = (c < 78) ? Wd[k * 78 + c] : 0.0f;
    }
    bf16x8 h8, l8; split8(f, h8, l8);
    ((bf16x8*)wdHi)[fr * 64 + ln] = h8;
    ((bf16x8*)wdLo)[fr * 64 + ln] = l8;
  }

  // per-lane biases
  const int cb = jt * 16 + n;
  const float bz  = b0[cb] + b1[cb];
  const float brr = b0[64 + cb] + b1[64 + cb];
  const float bxh = b0[128 + cb];
  const float bhh = b1[128 + cb];
  float bdv[5];
  #pragma unroll
  for (int nt = 0; nt < 5; ++nt) {
    int c = nt * 16 + n;
    bdv[nt] = (c < 78) ? bd[c] : 0.0f;
  }

  // ---- step 1 (h1 = gru(x,H), K=192) via 3 staged chunks ----
  f32x4 G0[4][4];
  #pragma unroll
  for (int mt = 0; mt < 4; ++mt) {
    G0[mt][0] = (f32x4){bz, bz, bz, bz};
    G0[mt][1] = (f32x4){brr, brr, brr, brr};
    G0[mt][2] = (f32x4){bxh, bxh, bxh, bxh};
    G0[mt][3] = (f32x4){bhh, bhh, bhh, bhh};
  }

  for (int ch = 0; ch < 3; ++ch) {
    for (int idx = tid; idx < 2048; idx += TPB) {
      int fr = idx >> 6, ln = idx & 63;
      int ntb = fr >> 1, ks = fr & 1;
      int lg = ln >> 4, lnn = ln & 15;
      int c = ntb * 16 + lnn;
      float f[8];
      #pragma unroll
      for (int j = 0; j < 8; ++j) {
        int k = ks * 32 + lg * 8 + j;
        float v;
        if (ch == 0)      v = (c < 192) ? Wk[k * 192 + c] : 0.0f;
        else if (ch == 1) v = (c < 192) ? Wk[(64 + k) * 192 + c] : 0.0f;
        else              v = (c < 128) ? Uk[k * 192 + c]
                              : ((c < 192) ? 0.0f : Uk[k * 192 + 128 + (c - 192)]);
        f[j] = v;
      }
      bf16x8 h8, l8; split8(f, h8, l8);
      ((bf16x8*)chkHi)[fr * 64 + ln] = h8;
      ((bf16x8*)chkLo)[fr * 64 + ln] = l8;
    }
    __syncthreads();

    #pragma unroll
    for (int mt = 0; mt < 4; ++mt) {
      bf16x8 Ah[2], Al[2];
      #pragma unroll
      for (int ks = 0; ks < 2; ++ks) {
        size_t grow = (size_t)(blockbase + row0g + mt * 16 + n);
        const float* src;
        if (ch == 0)      src = x + grow * 128 + ks * 32 + g * 8;
        else if (ch == 1) src = x + grow * 128 + 64 + ks * 32 + g * 8;
        else              src = Hin + grow * 64 + ks * 32 + g * 8;
        float4 v0 = *(const float4*)src;
        float4 v1 = *(const float4*)(src + 4);
        float f[8] = {v0.x, v0.y, v0.z, v0.w, v1.x, v1.y, v1.z, v1.w};
        split8(f, Ah[ks], Al[ks]);
      }
      #pragma unroll
      for (int gg = 0; gg < 4; ++gg) {
        int frb = (gg * 4 + jt) * 2;
        #pragma unroll
        for (int ks = 0; ks < 2; ++ks) {
          bf16x8 wh = ((const bf16x8*)chkHi)[(frb + ks) * 64 + lane];
          bf16x8 wl = ((const bf16x8*)chkLo)[(frb + ks) * 64 + lane];
          G0[mt][gg] = __builtin_amdgcn_mfma_f32_16x16x32_bf16(Ah[ks], wh, G0[mt][gg], 0, 0, 0);
          G0[mt][gg] = __builtin_amdgcn_mfma_f32_16x16x32_bf16(Al[ks], wh, G0[mt][gg], 0, 0, 0);
          G0[mt][gg] = __builtin_amdgcn_mfma_f32_16x16x32_bf16(Ah[ks], wl, G0[mt][gg], 0, 0, 0);
        }
      }
    }
    __syncthreads();
  }

  // epilogue of step 1 -> bufA
  #pragma unroll
  for (int mt = 0; mt < 4; ++mt)
    #pragma unroll
    for (int rr = 0; rr < 4; ++rr) {
      int lrow = row0g + mt * 16 + g * 4 + rr;
      float hold = Hin[(size_t)(blockbase + lrow) * 64 + jt * 16 + n];
      float z  = fsig(G0[mt][0][rr]);
      float rg = fsig(G0[mt][1][rr]);
      float cand = ftanh2(G0[mt][2][rr] + rg * G0[mt][3][rr]);
      bufA[lrow * 68 + jt * 16 + n] = cand + z * (hold - cand);
    }

  // ---- persistent combined gate weights (this wave's jt slice) -> 64 VGPR ----
  bf16x8 Wh[4][2], Wl[4][2];
  #pragma unroll
  for (int gg = 0; gg < 4; ++gg)
    #pragma unroll
    for (int ks = 0; ks < 2; ++ks) {
      int c = (gg * 4 + jt) * 16 + n;
      float f[8];
      #pragma unroll
      for (int j = 0; j < 8; ++j) {
        int k = ks * 32 + g * 8 + j;
        float v;
        if      (c < 128) v = Wk[k * 192 + c] + Uk[k * 192 + c];
        else if (c < 192) v = Wk[k * 192 + c];
        else              v = Uk[k * 192 + 128 + (c - 192)];
        f[j] = v;
      }
      split8(f, Wh[gg][ks], Wl[gg][ks]);
    }

  __syncthreads();

  // ---- 25 iterations: logits+softmax+store(h_s); gates -> h_{s+1} ----
  for (int s = 0; s < 25; ++s) {
    float* cur = (s & 1) ? bufB : bufA;
    float* nxt = (s & 1) ? bufA : bufB;

    {  // logits for rows row0l..+16 (wave-unique)
      bf16x8 Ah[2], Al[2];
      #pragma unroll
      for (int ks = 0; ks < 2; ++ks)
        splitA_lds(cur + (row0l + n) * 68 + ks * 32 + g * 8, Ah[ks], Al[ks]);
      f32x4 L[5];
      #pragma unroll
      for (int nt = 0; nt < 5; ++nt)
        L[nt] = (f32x4){bdv[nt], bdv[nt], bdv[nt], bdv[nt]};
      #pragma unroll
      for (int nt = 0; nt < 5; ++nt)
        #pragma unroll
        for (int ks = 0; ks < 2; ++ks) {
          bf16x8 wh = ((const bf16x8*)wdHi)[(nt * 2 + ks) * 64 + lane];
          bf16x8 wl = ((const bf16x8*)wdLo)[(nt * 2 + ks) * 64 + lane];
          L[nt] = __builtin_amdgcn_mfma_f32_16x16x32_bf16(Ah[ks], wh, L[nt], 0, 0, 0);
          L[nt] = __builtin_amdgcn_mfma_f32_16x16x32_bf16(Al[ks], wh, L[nt], 0, 0, 0);
          L[nt] = __builtin_amdgcn_mfma_f32_16x16x32_bf16(Ah[ks], wl, L[nt], 0, 0, 0);
        }
      #pragma unroll
      for (int rr = 0; rr < 4; ++rr) {
        float v0 = L[0][rr], v1 = L[1][rr], v2 = L[2][rr], v3 = L[3][rr];
        float v4 = (n < 14) ? L[4][rr] : -1e30f;
        float mx = fmaxf(fmaxf(fmaxf(v0, v1), fmaxf(v2, v3)), v4);
        mx = fmaxf(mx, dppror<0x128>(mx));
        mx = fmaxf(mx, dppror<0x124>(mx));
        mx = fmaxf(mx, dppror<0x122>(mx));
        mx = fmaxf(mx, dppror<0x121>(mx));
        float e0 = __expf(v0 - mx), e1 = __expf(v1 - mx);
        float e2 = __expf(v2 - mx), e3 = __expf(v3 - mx);
        float e4 = (n < 14) ? __expf(v4 - mx) : 0.0f;
        float sm = e0 + e1 + e2 + e3 + e4;
        sm += dppror<0x128>(sm);
        sm += dppror<0x124>(sm);
        sm += dppror<0x122>(sm);
        sm += dppror<0x121>(sm);
        float inv = __builtin_amdgcn_rcpf(sm);
        size_t grow = (size_t)blockbase + row0l + g * 4 + rr;
        float* orow = out + (grow * 25 + s) * 78;
        orow[n]      = e0 * inv;
        orow[16 + n] = e1 * inv;
        orow[32 + n] = e2 * inv;
        orow[48 + n] = e3 * inv;
        if (n < 14) orow[64 + n] = e4 * inv;
      }
    }

    if (s == 24) break;

    // gates: rows row0g..+64, this wave's jt cols; write nxt
    #pragma unroll
    for (int mt = 0; mt < 4; ++mt) {
      int r0 = row0g + mt * 16;
      bf16x8 Ah[2], Al[2];
      #pragma unroll
      for (int ks = 0; ks < 2; ++ks)
        splitA_lds(cur + (r0 + n) * 68 + ks * 32 + g * 8, Ah[ks], Al[ks]);
      f32x4 C0 = {bz, bz, bz, bz};
      f32x4 C1 = {brr, brr, brr, brr};
      f32x4 C2 = {bxh, bxh, bxh, bxh};
      f32x4 C3 = {bhh, bhh, bhh, bhh};
      #pragma unroll
      for (int ks = 0; ks < 2; ++ks) {
        C0 = __builtin_amdgcn_mfma_f32_16x16x32_bf16(Ah[ks], Wh[0][ks], C0, 0, 0, 0);
        C0 = __builtin_amdgcn_mfma_f32_16x16x32_bf16(Al[ks], Wh[0][ks], C0, 0, 0, 0);
        C0 = __builtin_amdgcn_mfma_f32_16x16x32_bf16(Ah[ks], Wl[0][ks], C0, 0, 0, 0);
        C1 = __builtin_amdgcn_mfma_f32_16x16x32_bf16(Ah[ks], Wh[1][ks], C1, 0, 0, 0);
        C1 = __builtin_amdgcn_mfma_f32_16x16x32_bf16(Al[ks], Wh[1][ks], C1, 0, 0, 0);
        C1 = __builtin_amdgcn_mfma_f32_16x16x32_bf16(Ah[ks], Wl[1][ks], C1, 0, 0, 0);
        C2 = __builtin_amdgcn_mfma_f32_16x16x32_bf16(Ah[ks], Wh[2][ks], C2, 0, 0, 0);
        C2 = __builtin_amdgcn_mfma_f32_16x16x32_bf16(Al[ks], Wh[2][ks], C2, 0, 0, 0);
        C2 = __builtin_amdgcn_mfma_f32_16x16x32_bf16(Ah[ks], Wl[2][ks], C2, 0, 0, 0);
        C3 = __builtin_amdgcn_mfma_f32_16x16x32_bf16(Ah[ks], Wh[3][ks], C3, 0, 0, 0);
        C3 = __builtin_amdgcn_mfma_f32_16x16x32_bf16(Al[ks], Wh[3][ks], C3, 0, 0, 0);
        C3 = __builtin_amdgcn_mfma_f32_16x16x32_bf16(Ah[ks], Wl[3][ks], C3, 0, 0, 0);
      }
      #pragma unroll
      for (int rr = 0; rr < 4; ++rr) {
        int lrow = r0 + g * 4 + rr;
        float hold = cur[lrow * 68 + jt * 16 + n];
        float z  = fsig(C0[rr]);
        float rg = fsig(C1[rr]);
        float cand = ftanh2(C2[rr] + rg * C3[rr]);
        nxt[lrow * 68 + jt * 16 + n] = cand + z * (hold - cand);
      }
    }
    __syncthreads();
  }
}

extern "C" void kernel_launch(void* const* d_in, const int* in_sizes, int n_in,
                              void* d_out, int out_size, void* d_ws, size_t ws_size,
                              hipStream_t stream) {
  const float* x   = (const float*)d_in[0];
  const float* H   = (const float*)d_in[1];
  const float* Wk  = (const float*)d_in[2];
  const float* Uk  = (const float*)d_in[3];
  const float* b   = (const float*)d_in[4];
  const float* Wd  = (const float*)d_in[5];
  const float* bd  = (const float*)d_in[6];
  float* out = (float*)d_out;
  (void)d_ws; (void)ws_size; (void)in_sizes; (void)n_in; (void)out_size;

  const int lds = 38912 * 4;  // 155648 B
  hipFuncSetAttribute((const void*)vgru_all,
                      hipFuncAttributeMaxDynamicSharedMemorySize, lds);
  vgru_all<<<dim3(256), dim3(TPB), lds, stream>>>(x, H, Wk, Uk, b, Wd, bd, out);
}